// Round 9
// baseline (155.813 us; speedup 1.0000x reference)
//
#include <hip/hip_runtime.h>
#include <hip/hip_bf16.h>
#include <hip/hip_cooperative_groups.h>

namespace cg = cooperative_groups;

#define EPSF 1e-8f

typedef short bf16x8 __attribute__((ext_vector_type(8)));
typedef float f32x4 __attribute__((ext_vector_type(4)));

__device__ __forceinline__ float bflo(unsigned u){ return __uint_as_float(u<<16); }
__device__ __forceinline__ float bfhi(unsigned u){ return __uint_as_float(u&0xffff0000u); }
__device__ __forceinline__ float bfu16(unsigned short u){ return __uint_as_float((unsigned)u<<16); }
__device__ __forceinline__ unsigned bfpack2(float a,float b){
    return (__float_as_uint(a)>>16)|(__float_as_uint(b)&0xffff0000u);
}
__device__ __forceinline__ unsigned short bfr16(float a){
    return (unsigned short)(__float_as_uint(a)>>16);
}
__device__ __forceinline__ float fastrcp(float x){ return __builtin_amdgcn_rcpf(x); }
__device__ __forceinline__ bf16x8 pack8(const float* v){
    union { unsigned u[4]; bf16x8 v8; } cv;
#pragma unroll
    for (int j = 0; j < 4; ++j) cv.u[j] = bfpack2(v[2*j], v[2*j+1]);
    return cv.v8;
}

// ===========================================================================
// Mega-kernel LDS map (63616 B -> 2 blocks/CU, coop grid 512):
//   0      slab f32[288][28]   (input taps, persistent all phases)   32256
//   32256  wLT  u16[28][132]   (weights bf16, transposed)             7424
//   39680  cbL  f32[128]
//   40192  smL f32[32] ; 40320 sizL f32[32] ; 40448 ktab u32[32]
//   40576  per-wave[4] x 3584: {Bu u32[32][20]; shL f32[128]; auxL f32[32];
//                               statb f32[96]}
//   54912  tile f32[128][17]   (phase-2 out staging / comb / entropy)
// Block = (b,h,half-row of 16 w's); wave = 4 locs; B state = f32 regs.
// ===========================================================================

template<int PHASE>
__device__ __forceinline__ void caps_phase(
    const float* __restrict__ slab, const unsigned short* __restrict__ wLT,
    const float* __restrict__ cbL, const float* __restrict__ smL,
    const float* __restrict__ sizL, const unsigned* __restrict__ ktab,
    unsigned* __restrict__ Bu, float* __restrict__ shL,
    float* __restrict__ auxL, float* __restrict__ statb,
    float* __restrict__ tile, float (&Breg)[4][16],
    const unsigned char* __restrict__ smemBase,
    int lane, int wid, int t, int bid,
    float* __restrict__ pmG, float* __restrict__ psG, float* __restrict__ ptG)
{
    const int lq = lane >> 4, l15 = lane & 15;
    float Mw[2] = {-1e30f, -1e30f}, Sw[2] = {0.f, 0.f}, Tw[2] = {0.f, 0.f};

#pragma unroll
    for (int L = 0; L < 4; ++L) {
        const int wloc = wid * 4 + L;
        const int wl3 = wloc + 3;

        if constexpr (PHASE == 0) {
            // vsum[k] = sum_ci v[ci][k]  (iter0 uniform-k identity)
            const int k2 = lane >> 1, half = lane & 1;
            float vs = 0.f;
            if (k2 < 27) {
                const float* sp = slab + half * 16 * 252 + ktab[k2] + wl3;
#pragma unroll
                for (int i = 0; i < 16; ++i) vs += sp[i * 252];
            }
            vs += __shfl_xor(vs, 1);
            if (half == 0 && k2 < 27) auxL[k2] = vs;
        } else {
            // stage B regs -> Bu as bf16 ci-pairs (cj rows)
#pragma unroll
            for (int mt = 0; mt < 2; ++mt)
#pragma unroll
            for (int reg = 0; reg < 4; ++reg)
#pragma unroll
            for (int nt = 0; nt < 2; ++nt) {
                const float me = Breg[L][mt*8 + nt*4 + reg];
                const float ot = __shfl_xor(me, 1);
                const unsigned pk = (l15 & 1) ? bfpack2(ot, me) : bfpack2(me, ot);
                if ((l15 & 1) == nt)
                    Bu[(mt*16 + lq*4 + reg)*20 + nt*8 + (l15 >> 1)] = pk;
            }
            // kmat A-frags: row cj = mt*16+l15, k(ci) = lq*8+j
            bf16x8 kmA[2];
#pragma unroll
            for (int mt = 0; mt < 2; ++mt) {
                const uint4 q = *(const uint4*)(Bu + (mt*16 + l15)*20 + lq*4);
                const unsigned uu[4] = {q.x, q.y, q.z, q.w};
                float ev[8];
#pragma unroll
                for (int j2 = 0; j2 < 4; ++j2) {
                    const int ci0 = lq*8 + 2*j2;
                    ev[2*j2]   = __expf(bflo(uu[j2]) - smL[ci0])   * sizL[ci0];
                    ev[2*j2+1] = __expf(bfhi(uu[j2]) - smL[ci0+1]) * sizL[ci0+1];
                }
                kmA[mt] = pack8(ev);
            }
            // vT B-frags: col kt = nt*16+l15, k(ci) = lq*8+j; kt==27 -> ones
            bf16x8 vtB[2];
#pragma unroll
            for (int nt = 0; nt < 2; ++nt) {
                const int kt = nt*16 + l15;
                const unsigned tb = ktab[kt];
                float vals[8];
#pragma unroll
                for (int j = 0; j < 8; ++j) {
                    const float sv = slab[(lq*8 + j)*252 + tb + wl3];
                    vals[j] = (kt < 27) ? sv : (kt == 27 ? 1.0f : 0.0f);
                }
                vtB[nt] = pack8(vals);
            }
            // matmul1: u[cj][kt] = kmat x vT
            f32x4 accu[2][2];
#pragma unroll
            for (int mt = 0; mt < 2; ++mt)
#pragma unroll
            for (int nt = 0; nt < 2; ++nt)
                accu[mt][nt] = __builtin_amdgcn_mfma_f32_16x16x32_bf16(
                    kmA[mt], vtB[nt], (f32x4){0.f,0.f,0.f,0.f}, 0, 0, 0);
            // u -> Bu (bf16 kt-pairs; overwrites B staging, reads done)
#pragma unroll
            for (int mt = 0; mt < 2; ++mt)
#pragma unroll
            for (int reg = 0; reg < 4; ++reg)
#pragma unroll
            for (int nt = 0; nt < 2; ++nt) {
                const float me = accu[mt][nt][reg];
                const float ot = __shfl_xor(me, 1);
                const unsigned pk = (l15 & 1) ? bfpack2(ot, me) : bfpack2(me, ot);
                if ((l15 & 1) == nt)
                    Bu[(mt*16 + lq*4 + reg)*20 + nt*8 + (l15 >> 1)] = pk;
            }
        }

        // S + squash for c = lane, lane+64
#pragma unroll
        for (int cc = 0; cc < 2; ++cc) {
            const int c = lane + cc*64;
            float S;
            if constexpr (PHASE == 0) {
                S = 0.f;
#pragma unroll
                for (int k = 0; k < 27; ++k)
                    S = fmaf(bfu16(wLT[k*132 + c]), auxL[k], S);
                S = S * (1.0f/32768.0f) + cbL[c] * (1.0f/1024.0f);
            } else {
                const unsigned* up = Bu + (c >> 2)*20;
                S = 0.f;
#pragma unroll
                for (int p = 0; p < 13; ++p) {
                    const unsigned u = up[p];
                    S = fmaf(bfu16(wLT[(2*p)*132 + c]),   bflo(u), S);
                    S = fmaf(bfu16(wLT[(2*p+1)*132 + c]), bfhi(u), S);
                }
                const unsigned u13 = up[13];
                S = fmaf(bfu16(wLT[26*132 + c]), bflo(u13), S);
                S = fmaf(cbL[c], bfhi(u13), S);      // + cb * K1[cj]
            }
            const float sq = fabsf(S) * S * fastrcp(1.f + S*S + EPSF);
            if constexpr (PHASE == 2) tile[c*17 + wloc] = sq;
            else shL[c] = sq;
        }
        if constexpr (PHASE == 2) continue;

        // ws[cj][k] = sum_nj sh*w -> Bu overlay ; cbs -> auxL
        {
            const int k0 = 2*l15, k1 = k0 + 1;
#pragma unroll
            for (int i = 0; i < 8; ++i) {
                const int cj = lq + 4*i;
                float v0 = 0.f, v1 = 0.f;
                if (k0 < 27) {
#pragma unroll
                    for (int nj = 0; nj < 4; ++nj)
                        v0 = fmaf(shL[cj*4+nj], bfu16(wLT[k0*132 + cj*4 + nj]), v0);
                }
                if (k1 < 27) {
#pragma unroll
                    for (int nj = 0; nj < 4; ++nj)
                        v1 = fmaf(shL[cj*4+nj], bfu16(wLT[k1*132 + cj*4 + nj]), v1);
                }
                Bu[cj*20 + l15] = bfpack2(v0, v1);
            }
            if (lane < 32) {
                float cv = 0.f;
#pragma unroll
                for (int nj = 0; nj < 4; ++nj)
                    cv = fmaf(shL[lane*4+nj], cbL[lane*4+nj], cv);
                auxL[lane] = cv;
            }
        }
        // matmul2: B_upd = ws x v
        bf16x8 wsA[2], vB[2];
#pragma unroll
        for (int mt = 0; mt < 2; ++mt) {
            union { uint4 q4; bf16x8 v8; } cv;
            cv.q4 = *(const uint4*)(Bu + (mt*16 + l15)*20 + lq*4);
            wsA[mt] = cv.v8;
        }
#pragma unroll
        for (int nt = 0; nt < 2; ++nt) {
            const int ci = nt*16 + l15;
            float vals[8];
#pragma unroll
            for (int j = 0; j < 8; ++j) {
                const int k = lq*8 + j;
                const float sv = slab[ci*252 + ktab[k] + wl3];
                vals[j] = (k < 27) ? sv : 0.0f;
            }
            vB[nt] = pack8(vals);
        }
        f32x4 accb[2][2];
#pragma unroll
        for (int mt = 0; mt < 2; ++mt)
#pragma unroll
        for (int nt = 0; nt < 2; ++nt)
            accb[mt][nt] = __builtin_amdgcn_mfma_f32_16x16x32_bf16(
                wsA[mt], vB[nt], (f32x4){0.f,0.f,0.f,0.f}, 0, 0, 0);

        // B_new = [B_prev +] upd + cbs ; per-ci stats over 32 cj
        float m2[2], s2[2], T2[2];
#pragma unroll
        for (int nt = 0; nt < 2; ++nt) {
            float bv[8];
#pragma unroll
            for (int mt = 0; mt < 2; ++mt)
#pragma unroll
            for (int reg = 0; reg < 4; ++reg) {
                const int cj = mt*16 + lq*4 + reg;
                float val = accb[mt][nt][reg] + auxL[cj];
                if constexpr (PHASE == 1) val += Breg[L][mt*8 + nt*4 + reg];
                Breg[L][mt*8 + nt*4 + reg] = val;
                bv[mt*4 + reg] = val;
            }
            float m = bv[0];
#pragma unroll
            for (int i = 1; i < 8; ++i) m = fmaxf(m, bv[i]);
            float s = 0.f, T = 0.f;
#pragma unroll
            for (int i = 0; i < 8; ++i) {
                const float d = bv[i] - m;
                const float e = __expf(d);
                s += e; T += e*d;
            }
            m2[nt] = m; s2[nt] = s; T2[nt] = T;
        }
#pragma unroll
        for (int nt = 0; nt < 2; ++nt) {
#pragma unroll
            for (int off = 16; off <= 32; off <<= 1) {   // lanes ^16,^32 share ci
                const float mo = __shfl_xor(m2[nt], off);
                const float so = __shfl_xor(s2[nt], off);
                const float To = __shfl_xor(T2[nt], off);
                const float nm = fmaxf(m2[nt], mo);
                const float ea = __expf(m2[nt]-nm), eb = __expf(mo-nm);
                T2[nt] = ea*(T2[nt] + s2[nt]*(m2[nt]-nm)) + eb*(To + so*(mo-nm));
                s2[nt] = ea*s2[nt] + eb*so;
                m2[nt] = nm;
            }
            const float nm = fmaxf(Mw[nt], m2[nt]);      // fold loc into running
            const float ea = __expf(Mw[nt]-nm), eb = __expf(m2[nt]-nm);
            Tw[nt] = ea*(Tw[nt] + Sw[nt]*(Mw[nt]-nm)) + eb*(T2[nt] + s2[nt]*(m2[nt]-nm));
            Sw[nt] = ea*Sw[nt] + eb*s2[nt];
            Mw[nt] = nm;
        }
    }

    if constexpr (PHASE == 2) return;

    if (lane < 16) {
#pragma unroll
        for (int nt = 0; nt < 2; ++nt) {
            const int ci = nt*16 + lane;
            statb[ci] = Mw[nt]; statb[32+ci] = Sw[nt]; statb[64+ci] = Tw[nt];
        }
    }
    __syncthreads();
    if (t < 32) {            // merge 4 waves -> block partial (global)
        float M = -1e30f, Z = 0.f, T = 0.f;
#pragma unroll
        for (int wv = 0; wv < 4; ++wv) {
            const float* sb = (const float*)(smemBase + 40576 + wv*3584 + 3200);
            const float mo = sb[t], so = sb[32+t], To = sb[64+t];
            const float nm = fmaxf(M, mo);
            const float ea = __expf(M-nm), eb = __expf(mo-nm);
            T = ea*(T + Z*(M-nm)) + eb*(To + so*(mo-nm));
            Z = ea*Z + eb*so;
            M = nm;
        }
        pmG[bid*32 + t] = M;
        psG[bid*32 + t] = Z;
        if constexpr (PHASE == 1) ptG[bid*32 + t] = T;
    }
}

// every block combines its own batch's 64 partials -> smL/sizL (1 sync/round)
__device__ __forceinline__ void combine_stats(const float* __restrict__ pmG,
                                              const float* __restrict__ psG,
                                              int b, int t, float* __restrict__ comb,
                                              float* __restrict__ smL,
                                              float* __restrict__ sizL) {
    const int seg = t >> 5, ci = t & 31;
    float M = -1e30f, Z = 0.f;
    for (int j = 0; j < 8; ++j) {
        const int idx = (b*64 + seg*8 + j)*32 + ci;
        const float m = pmG[idx], s = psG[idx];
        const float nm = fmaxf(M, m);
        Z = Z*__expf(M-nm) + s*__expf(m-nm);
        M = nm;
    }
    comb[seg*32 + ci] = M; comb[256 + seg*32 + ci] = Z;
    __syncthreads();
    if (t < 32) {
        float Mg = -1e30f, Zg = 0.f;
        for (int q = 0; q < 8; ++q) {
            const float m = comb[q*32+t], s = comb[256 + q*32+t];
            const float nm = fmaxf(Mg, m);
            Zg = Zg*__expf(Mg-nm) + s*__expf(m-nm);
            Mg = nm;
        }
        smL[t] = Mg; sizL[t] = 1.0f / Zg;
    }
}

__global__ __launch_bounds__(256, 2) void k_mega(
    const float* __restrict__ in, const float* __restrict__ cw,
    const float* __restrict__ cb, float* __restrict__ out,
    float* __restrict__ pm0, float* __restrict__ ps0,
    float* __restrict__ pm1, float* __restrict__ ps1, float* __restrict__ pt1)
{
    cg::grid_group grid = cg::this_grid();
    __shared__ __align__(16) unsigned char smem[63616];
    float* slab = (float*)smem;
    unsigned short* wLT = (unsigned short*)(smem + 32256);
    float* cbL  = (float*)(smem + 39680);
    float* smL  = (float*)(smem + 40192);
    float* sizL = (float*)(smem + 40320);
    unsigned* ktab = (unsigned*)(smem + 40448);
    float* tile = (float*)(smem + 54912);

    const int t = threadIdx.x;
    const int lane = t & 63, wid = t >> 6;
    const int bid = blockIdx.x;
    const int bh = bid >> 1, b = bid >> 6, h = bh & 31;
    const int w0 = (bid & 1) << 4;

    unsigned char* wb = smem + 40576 + (size_t)wid * 3584;
    unsigned* Bu  = (unsigned*)wb;
    float* shL    = (float*)(wb + 2560);
    float* auxL   = (float*)(wb + 3072);
    float* statb  = (float*)(wb + 3200);

    // ---- prologue (once): slab, weights, bias, tap-offset table ----------
    for (int j = t; j < 1728; j += 256) {
        const int r = j / 6, q = j - r * 6;
        const int ci2 = r / 9, rem = r - ci2 * 9, kd = rem / 3, dy = rem - kd * 3;
        const int y = h + dy - 1;
        const int x0 = w0 - 4 + q * 4;
        float4 f = {0.f, 0.f, 0.f, 0.f};
        if ((unsigned)y < 32u && (unsigned)x0 < 32u)
            f = *(const float4*)(in + (((size_t)(b*32+ci2)*8 + kd)*32 + y)*32 + x0);
        *(float4*)(slab + r*28 + q*4) = f;
    }
    for (int j = t; j < 3456; j += 256) {
        const int c = j / 27, k = j - c*27;
        wLT[k*132 + c] = bfr16(cw[j]);
    }
    if (t < 128) cbL[t] = cb[t];
    if (t < 32) {
        const int k = t < 27 ? t : 26;        // clamped for kt>=27 (masked later)
        const int kd = k/9, r9 = k - kd*9, dy = r9/3, dx = r9 - dy*3;
        ktab[t] = (unsigned)((kd*3+dy)*28 + dx);
    }
    __syncthreads();

    float Breg[4][16];

    caps_phase<0>(slab, wLT, cbL, smL, sizL, ktab, Bu, shL, auxL, statb, tile,
                  Breg, smem, lane, wid, t, bid, pm0, ps0, pt1);
    grid.sync();
    combine_stats(pm0, ps0, b, t, tile, smL, sizL);
    __syncthreads();

    caps_phase<1>(slab, wLT, cbL, smL, sizL, ktab, Bu, shL, auxL, statb, tile,
                  Breg, smem, lane, wid, t, bid, pm1, ps1, pt1);
    grid.sync();
    combine_stats(pm1, ps1, b, t, tile, smL, sizL);
    __syncthreads();

    caps_phase<2>(slab, wLT, cbL, smL, sizL, ktab, Bu, shL, auxL, statb, tile,
                  Breg, smem, lane, wid, t, bid, pm1, ps1, pt1);
    __syncthreads();

    // flush tile -> out [b][c][h][w0..w0+15]  (64B-coalesced segments)
#pragma unroll
    for (int r = 0; r < 8; ++r) {
        const int idx = t + 256*r;
        const int c = idx >> 4, wl = idx & 15;
        out[((size_t)(b*128 + c))*1024 + (size_t)h*32 + w0 + wl] = tile[c*17 + wl];
    }

    // entropy: block 0 recombines phase-1 partials (written pre-sync2)
    if (bid == 0) {
        __syncthreads();
        float* er = tile;
        const int bb = t >> 5, ci = t & 31;
        float M = -1e30f, Z = 0.f, T = 0.f;
        for (int j = 0; j < 64; ++j) {
            const int idx = (bb*64 + j)*32 + ci;
            const float mo = pm1[idx], so = ps1[idx], To = pt1[idx];
            const float nm = fmaxf(M, mo);
            const float ea = __expf(M-nm), eb = __expf(mo-nm);
            T = ea*(T + Z*(M-nm)) + eb*(To + so*(mo-nm));
            Z = ea*Z + eb*so;
            M = nm;
        }
        // ent = (lnZ - T/Z)/ln(32768); eps-in-log shift ~3e-5 << 2e-2 tol
        er[t] = (logf(Z) - T/Z) * (1.0f/10.39720770839918f);
        __syncthreads();
        for (int s2 = 128; s2 > 0; s2 >>= 1) {
            if (t < s2) er[t] += er[t + s2];
            __syncthreads();
        }
        if (t == 0) out[1048576] = er[0] * (1.0f/256.0f);
    }
}

// ===========================================================================
// Fallback: proven round-8 pipeline (used only if cooperative launch fails).
// ===========================================================================
template<int PHASE>
__global__ __launch_bounds__(256, 2) void k_caps(
    const float* __restrict__ in, const float* __restrict__ cw,
    const float* __restrict__ cb, unsigned* __restrict__ Bpk,
    const float* __restrict__ sm_in, const float* __restrict__ siz_in,
    float* __restrict__ pm, float* __restrict__ ps, float* __restrict__ pt,
    float* __restrict__ shat) {
    __shared__ __align__(16) unsigned char smem[61440];
    unsigned short* wLT = (unsigned short*)smem;
    float* cbL  = (float*)(smem + 7424);
    float* smL  = (float*)(smem + 7936);
    float* sizL = (float*)(smem + 8064);
    float* slab = (float*)(smem + 8192);

    const int t = threadIdx.x;
    const int lane = t & 63, wid = t >> 6;
    const int bid = blockIdx.x;
    const int bh = bid >> 3, b = bh >> 5, h = bh & 31;
    const int w0 = (bid & 7) << 2;
    const int l15 = lane & 15, lq = lane >> 4;

    float*    Blu = (float*)(smem + 8192 + wid * 7168);
    unsigned* wsL = (unsigned*)(smem + 8192 + wid * 7168 + 4608);
    unsigned* vL  = (unsigned*)(smem + 36864 + wid * 2560);
    unsigned* vTL = (unsigned*)(smem + 47104 + wid * 2560);
    float* shL   = (float*)(smem + 57344 + wid * 1024);
    float* auxL  = (float*)(smem + 57344 + wid * 1024 + 512);
    float* statb = (float*)(smem + 57344 + wid * 1024 + 640);

    for (int j = t; j < 864; j += 256) {
        const int r = j / 3, q = j - r * 3;
        const int ci2 = r / 9, rem = r - ci2 * 9, kd = rem / 3, dy = rem - kd * 3;
        const int y = h + dy - 1;
        const int x0 = w0 - 4 + q * 4;
        float4 f = {0.f, 0.f, 0.f, 0.f};
        if ((unsigned)y < 32u && (unsigned)x0 < 32u)
            f = *reinterpret_cast<const float4*>(
                in + (((size_t)(b * 32 + ci2) * 8 + kd) * 32 + y) * 32 + x0);
        *reinterpret_cast<float4*>(slab + r * 12 + q * 4) = f;
    }
    for (int j = t; j < 3456; j += 256) {
        const int c = j / 27, k = j - c * 27;
        wLT[k * 132 + c] = bfr16(cw[j]);
    }
    if (t < 128) cbL[t] = cb[t];
    if constexpr (PHASE >= 1) {
        if (t < 32) { smL[t] = sm_in[b * 32 + t]; sizL[t] = siz_in[b * 32 + t]; }
    }
    __syncthreads();

    {
        const int half = lane & 1, idx = lane >> 1;
        if constexpr (PHASE != 2) {
            const float* srow = slab + idx * 108 + wid + 3;
            unsigned pk[8];
            if (half == 0) {
#pragma unroll
                for (int j = 0; j < 8; ++j) {
                    float a, bb;
                    { const int k = 2 * j;     const int kd = k / 9, r9 = k - kd * 9, dy = r9 / 3, dx = r9 - dy * 3;
                      a  = srow[(kd * 3 + dy) * 12 + dx]; }
                    { const int k = 2 * j + 1; const int kd = k / 9, r9 = k - kd * 9, dy = r9 / 3, dx = r9 - dy * 3;
                      bb = srow[(kd * 3 + dy) * 12 + dx]; }
                    pk[j] = bfpack2(a, bb);
                }
            } else {
#pragma unroll
                for (int j = 0; j < 8; ++j) {
                    const int k0 = 16 + 2 * j, k1 = k0 + 1;
                    float a = 0.f, bb = 0.f;
                    if (k0 < 27) { const int kd = k0 / 9, r9 = k0 - kd * 9, dy = r9 / 3, dx = r9 - dy * 3;
                                   a  = srow[(kd * 3 + dy) * 12 + dx]; }
                    if (k1 < 27) { const int kd = k1 / 9, r9 = k1 - kd * 9, dy = r9 / 3, dx = r9 - dy * 3;
                                   bb = srow[(kd * 3 + dy) * 12 + dx]; }
                    pk[j] = bfpack2(a, bb);
                }
            }
            uint4* dst = (uint4*)(vL + idx * 20 + half * 8);
            dst[0] = make_uint4(pk[0], pk[1], pk[2], pk[3]);
            dst[1] = make_uint4(pk[4], pk[5], pk[6], pk[7]);
        }
        {
            const int kt = idx;
            float vals[16];
            if (kt < 27) {
                const int kd = kt / 9, r9 = kt - kd * 9, dy = r9 / 3, dx = r9 - dy * 3;
                const float* sp = slab + (kd * 3 + dy) * 12 + wid + 3 + dx + (half * 16) * 108;
#pragma unroll
                for (int i = 0; i < 16; ++i) vals[i] = sp[i * 108];
            } else {
                const float fv = (kt == 27) ? 1.0f : 0.0f;
#pragma unroll
                for (int i = 0; i < 16; ++i) vals[i] = fv;
            }
            if constexpr (PHASE >= 1) {
                unsigned pk[8];
#pragma unroll
                for (int j = 0; j < 8; ++j) pk[j] = bfpack2(vals[2 * j], vals[2 * j + 1]);
                uint4* dst = (uint4*)(vTL + kt * 20 + half * 8);
                dst[0] = make_uint4(pk[0], pk[1], pk[2], pk[3]);
                dst[1] = make_uint4(pk[4], pk[5], pk[6], pk[7]);
            } else {
                float vs = 0.f;
#pragma unroll
                for (int i = 0; i < 16; ++i) vs += vals[i];
                vs += __shfl_xor(vs, 1);
                if (half == 0 && kt < 27) auxL[kt] = vs;
            }
        }
    }
    __syncthreads();

    const size_t loc = (size_t)bh * 32 + w0 + wid;

    float b1v[16];
    if constexpr (PHASE >= 1) {
        const uint4* Bg = (const uint4*)(Bpk + loc * 512 + (size_t)lane * 8);
        const uint4 q0 = Bg[0], q1 = Bg[1];
        const unsigned pk[8] = {q0.x, q0.y, q0.z, q0.w, q1.x, q1.y, q1.z, q1.w};
#pragma unroll
        for (int e = 0; e < 8; ++e) { b1v[2 * e] = bflo(pk[e]); b1v[2 * e + 1] = bfhi(pk[e]); }
#pragma unroll
        for (int mt = 0; mt < 2; ++mt)
#pragma unroll
        for (int nt = 0; nt < 2; ++nt)
#pragma unroll
        for (int reg = 0; reg < 4; ++reg)
            Blu[(mt * 16 + lq * 4 + reg) * 36 + nt * 16 + l15] = b1v[mt * 8 + nt * 4 + reg];
    }

    if constexpr (PHASE >= 1) {
        float sm8[8], sz8[8];
#pragma unroll
        for (int j = 0; j < 8; ++j) { const int ci = lq * 8 + j; sm8[j] = smL[ci]; sz8[j] = sizL[ci]; }
        bf16x8 kmA[2];
#pragma unroll
        for (int mt = 0; mt < 2; ++mt) {
            const float* rp = Blu + (mt * 16 + l15) * 36 + lq * 8;
            union { unsigned u[4]; bf16x8 v; } cv;
#pragma unroll
            for (int j2 = 0; j2 < 4; ++j2) {
                const float e0 = __expf(rp[2 * j2]     - sm8[2 * j2])     * sz8[2 * j2];
                const float e1 = __expf(rp[2 * j2 + 1] - sm8[2 * j2 + 1]) * sz8[2 * j2 + 1];
                cv.u[j2] = bfpack2(e0, e1);
            }
            kmA[mt] = cv.v;
        }
        bf16x8 vtB[2];
#pragma unroll
        for (int nt = 0; nt < 2; ++nt) {
            union { uint4 q; bf16x8 v; } cv;
            cv.q = *(const uint4*)(vTL + (nt * 16 + l15) * 20 + lq * 4);
            vtB[nt] = cv.v;
        }
        f32x4 accu[2][2];
#pragma unroll
        for (int mt = 0; mt < 2; ++mt)
#pragma unroll
        for (int nt = 0; nt < 2; ++nt) {
            accu[mt][nt] = (f32x4){0.f, 0.f, 0.f, 0.f};
            accu[mt][nt] = __builtin_amdgcn_mfma_f32_16x16x32_bf16(kmA[mt], vtB[nt], accu[mt][nt], 0, 0, 0);
        }
#pragma unroll
        for (int mt = 0; mt < 2; ++mt)
#pragma unroll
        for (int nt = 0; nt < 2; ++nt)
#pragma unroll
        for (int reg = 0; reg < 4; ++reg)
            Blu[(mt * 16 + lq * 4 + reg) * 36 + nt * 16 + l15] = accu[mt][nt][reg];
    }

#pragma unroll
    for (int cc2 = 0; cc2 < 2; ++cc2) {
        const int c = lane + cc2 * 64;
        float S;
        if constexpr (PHASE == 0) {
            S = 0.f;
#pragma unroll
            for (int k = 0; k < 27; ++k) S = fmaf(bfu16(wLT[k * 132 + c]), auxL[k], S);
            S = S * (1.0f / 32768.0f) + cbL[c] * (1.0f / 1024.0f);
        } else {
            const float* up = Blu + (c >> 2) * 36;
            S = cbL[c] * up[27];
#pragma unroll
            for (int k = 0; k < 27; ++k) S = fmaf(bfu16(wLT[k * 132 + c]), up[k], S);
        }
        const float sq = fabsf(S) * S * fastrcp(1.f + S * S + EPSF);
        if constexpr (PHASE == 2) shat[loc * 128 + c] = sq;
        else shL[c] = sq;
    }
    if constexpr (PHASE == 2) return;

#pragma unroll
    for (int i = 0; i < 8; ++i) {
        const int cj = lq + 4 * i;
        const int k0 = 2 * l15, k1 = k0 + 1;
        float v0 = 0.f, v1 = 0.f;
        if (k0 < 27) {
#pragma unroll
            for (int nj = 0; nj < 4; ++nj)
                v0 = fmaf(shL[cj * 4 + nj], bfu16(wLT[k0 * 132 + cj * 4 + nj]), v0);
        }
        if (k1 < 27) {
#pragma unroll
            for (int nj = 0; nj < 4; ++nj)
                v1 = fmaf(shL[cj * 4 + nj], bfu16(wLT[k1 * 132 + cj * 4 + nj]), v1);
        }
        wsL[cj * 20 + l15] = bfpack2(v0, v1);
    }
    if (lane < 32) {
        float cv = 0.f;
#pragma unroll
        for (int nj = 0; nj < 4; ++nj) cv = fmaf(shL[lane * 4 + nj], cbL[lane * 4 + nj], cv);
        auxL[lane] = cv;
    }

    bf16x8 wsA[2], vB[2];
#pragma unroll
    for (int mt = 0; mt < 2; ++mt) {
        union { uint4 q; bf16x8 v; } cv;
        cv.q = *(const uint4*)(wsL + (mt * 16 + l15) * 20 + lq * 4);
        wsA[mt] = cv.v;
    }
#pragma unroll
    for (int nt = 0; nt < 2; ++nt) {
        union { uint4 q; bf16x8 v; } cv;
        cv.q = *(const uint4*)(vL + (nt * 16 + l15) * 20 + lq * 4);
        vB[nt] = cv.v;
    }
    f32x4 accb[2][2];
#pragma unroll
    for (int mt = 0; mt < 2; ++mt)
#pragma unroll
    for (int nt = 0; nt < 2; ++nt) {
        accb[mt][nt] = (f32x4){0.f, 0.f, 0.f, 0.f};
        accb[mt][nt] = __builtin_amdgcn_mfma_f32_16x16x32_bf16(wsA[mt], vB[nt], accb[mt][nt], 0, 0, 0);
    }

    float cbs8[2][4];
#pragma unroll
    for (int mt = 0; mt < 2; ++mt)
#pragma unroll
    for (int reg = 0; reg < 4; ++reg) cbs8[mt][reg] = auxL[mt * 16 + lq * 4 + reg];

    float bnew[16];
#pragma unroll
    for (int mt = 0; mt < 2; ++mt)
#pragma unroll
    for (int nt = 0; nt < 2; ++nt)
#pragma unroll
    for (int reg = 0; reg < 4; ++reg) {
        float val = accb[mt][nt][reg] + cbs8[mt][reg];
        if constexpr (PHASE == 1) val += b1v[mt * 8 + nt * 4 + reg];
        bnew[mt * 8 + nt * 4 + reg] = val;
    }
    {
        unsigned pk[8];
#pragma unroll
        for (int e = 0; e < 8; ++e) pk[e] = bfpack2(bnew[2 * e], bnew[2 * e + 1]);
        uint4* Bg = (uint4*)(Bpk + loc * 512 + (size_t)lane * 8);
        Bg[0] = make_uint4(pk[0], pk[1], pk[2], pk[3]);
        Bg[1] = make_uint4(pk[4], pk[5], pk[6], pk[7]);
    }
    float m2[2], s2[2], T2[2];
#pragma unroll
    for (int nt = 0; nt < 2; ++nt) {
        float m = -1e30f;
#pragma unroll
        for (int mt = 0; mt < 2; ++mt)
#pragma unroll
        for (int reg = 0; reg < 4; ++reg) m = fmaxf(m, bnew[mt * 8 + nt * 4 + reg]);
        float s = 0.f, T = 0.f;
#pragma unroll
        for (int mt = 0; mt < 2; ++mt)
#pragma unroll
        for (int reg = 0; reg < 4; ++reg) {
            const float d = bnew[mt * 8 + nt * 4 + reg] - m;
            const float e = __expf(d);
            s += e; T += e * d;
        }
        m2[nt] = m; s2[nt] = s; T2[nt] = T;
#pragma unroll
        for (int off = 16; off <= 32; off <<= 1) {
            const float mo = __shfl_xor(m2[nt], off);
            const float so = __shfl_xor(s2[nt], off);
            const float To = __shfl_xor(T2[nt], off);
            const float nm = fmaxf(m2[nt], mo);
            const float ea = __expf(m2[nt] - nm), eb = __expf(mo - nm);
            T2[nt] = ea * (T2[nt] + s2[nt] * (m2[nt] - nm)) + eb * (To + so * (mo - nm));
            s2[nt] = ea * s2[nt] + eb * so;
            m2[nt] = nm;
        }
    }
    if (lane < 16) {
#pragma unroll
        for (int nt = 0; nt < 2; ++nt) {
            const int ci = nt * 16 + lane;
            statb[ci] = m2[nt]; statb[32 + ci] = s2[nt]; statb[64 + ci] = T2[nt];
        }
    }
    __syncthreads();
    if (t < 32) {
        float M = -1e30f, Z = 0.f, T = 0.f;
#pragma unroll
        for (int wv = 0; wv < 4; ++wv) {
            const float* sw = (const float*)(smem + 57344 + wv * 1024 + 640);
            const float mo = sw[t], so = sw[32 + t], To = sw[64 + t];
            const float nm = fmaxf(M, mo);
            const float ea = __expf(M - nm), eb = __expf(mo - nm);
            T = ea * (T + Z * (M - nm)) + eb * (To + so * (mo - nm));
            Z = ea * Z + eb * so;
            M = nm;
        }
        pm[bid * 32 + t] = M;
        ps[bid * 32 + t] = Z;
        if constexpr (PHASE == 1) pt[bid * 32 + t] = T;
    }
}

template <int NPART, bool ENT>
__global__ __launch_bounds__(256) void k_comb(const float* __restrict__ pm,
                                              const float* __restrict__ ps,
                                              const float* __restrict__ pt,
                                              float* __restrict__ sm,
                                              float* __restrict__ siz,
                                              float* __restrict__ entp) {
    const int b = blockIdx.x, t = threadIdx.x;
    const int ci = t & 31, seg = t >> 5;
    constexpr int PER = NPART / 8;
    __shared__ float red[3][8][33];

    float M = -1e30f;
    for (int k = 0; k < PER; ++k)
        M = fmaxf(M, pm[((size_t)b * NPART + seg * PER + k) * 32 + ci]);
    red[0][seg][ci] = M;
    __syncthreads();
    float Mg = red[0][0][ci];
#pragma unroll
    for (int q = 1; q < 8; ++q) Mg = fmaxf(Mg, red[0][q][ci]);

    float Z = 0.0f, T = 0.0f;
    for (int k = 0; k < PER; ++k) {
        const size_t i = ((size_t)b * NPART + seg * PER + k) * 32 + ci;
        const float dm = pm[i] - Mg;
        const float e = __expf(dm);
        Z += ps[i] * e;
        if constexpr (ENT) T += (pt[i] + ps[i] * dm) * e;
    }
    red[1][seg][ci] = Z;
    if constexpr (ENT) red[2][seg][ci] = T;
    __syncthreads();
    if (t < 32) {
        float Zt = 0.0f, Tt = 0.0f;
#pragma unroll
        for (int q = 0; q < 8; ++q) {
            Zt += red[1][q][ci];
            if constexpr (ENT) Tt += red[2][q][ci];
        }
        sm[b * 32 + ci] = Mg;
        siz[b * 32 + ci] = 1.0f / Zt;
        if constexpr (ENT)
            entp[b * 32 + ci] = (logf(Zt) - Tt / Zt) * (1.0f / 10.39720770839918f);
    }
}

__global__ __launch_bounds__(256) void k_out(const float* __restrict__ shat,
                                             const float* __restrict__ entp,
                                             float* __restrict__ out) {
    __shared__ float tile[32][129];
    const int bh = blockIdx.x;
    const int b = bh >> 5, h = bh & 31;
    const int t = threadIdx.x;
    const float4* sp = reinterpret_cast<const float4*>(shat + (size_t)bh * 4096);
#pragma unroll
    for (int j = 0; j < 4; ++j) {
        const int idx = t + j * 256;
        const float4 f = sp[idx];
        const int w = idx >> 5;
        const int c4 = (idx & 31) * 4;
        tile[w][c4 + 0] = f.x; tile[w][c4 + 1] = f.y;
        tile[w][c4 + 2] = f.z; tile[w][c4 + 3] = f.w;
    }
    __syncthreads();
    const int c = t >> 1, half = t & 1;
    float* op = out + (((size_t)b * 128 + c) * 32 + h) * 32 + half * 16;
#pragma unroll
    for (int j = 0; j < 16; ++j) op[j] = tile[half * 16 + j][c];

    if (bh == 0) {
        __shared__ float er[256];
        er[t] = entp[t];
        __syncthreads();
        for (int s2 = 128; s2 > 0; s2 >>= 1) {
            if (t < s2) er[t] += er[t + s2];
            __syncthreads();
        }
        if (t == 0) out[1048576] = er[0] * (1.0f / 256.0f);
    }
}

// ===========================================================================
extern "C" void kernel_launch(void* const* d_in, const int* in_sizes, int n_in,
                              void* d_out, int out_size, void* d_ws, size_t ws_size,
                              hipStream_t stream) {
    const float* in = (const float*)d_in[0];   // (8,32,8,32,32)
    const float* cw = (const float*)d_in[1];   // (128,1,3,3,3)
    const float* cb = (const float*)d_in[2];   // (128,)
    float* out = (float*)d_out;                // 1048576 + 1 floats

    // cooperative path workspace (tiny)
    float* cpm0 = (float*)d_ws;                // [512*32] each
    float* cps0 = cpm0 + 16384;
    float* cpm1 = cps0 + 16384;
    float* cps1 = cpm1 + 16384;
    float* cpt1 = cps1 + 16384;

    void* args[] = {(void*)&in, (void*)&cw, (void*)&cb, (void*)&out,
                    (void*)&cpm0, (void*)&cps0, (void*)&cpm1, (void*)&cps1, (void*)&cpt1};
    hipError_t err = hipLaunchCooperativeKernel(reinterpret_cast<void*>(k_mega),
                                                dim3(512), dim3(256), args, 0, stream);
    if (err == hipSuccess) return;
    (void)hipGetLastError();   // clear sticky error, take proven fallback path

    // ---- fallback: round-8 pipeline ----
    unsigned* Bpk = (unsigned*)d_ws;           // 16 MiB
    float* shat = (float*)(Bpk + 4194304);     // 4 MiB
    float* pm0  = shat + 1048576;
    float* ps0  = pm0 + 65536;
    float* pm1  = ps0 + 65536;
    float* ps1  = pm1 + 65536;
    float* pt1  = ps1 + 65536;
    float* sm0  = pt1 + 65536;
    float* siz0 = sm0 + 256;
    float* sm1  = siz0 + 256;
    float* siz1 = sm1 + 256;
    float* entp = siz1 + 256;

    k_caps<0><<<2048, 256, 0, stream>>>(in, cw, cb, Bpk, sm0, siz0, pm0, ps0, pt1, shat);
    k_comb<256, false><<<8, 256, 0, stream>>>(pm0, ps0, nullptr, sm0, siz0, nullptr);
    k_caps<1><<<2048, 256, 0, stream>>>(in, cw, cb, Bpk, sm0, siz0, pm1, ps1, pt1, shat);
    k_comb<256, true><<<8, 256, 0, stream>>>(pm1, ps1, pt1, sm1, siz1, entp);
    k_caps<2><<<2048, 256, 0, stream>>>(in, cw, cb, Bpk, sm1, siz1, pm1, ps1, pt1, shat);
    k_out<<<256, 256, 0, stream>>>(shat, entp, out);
}

// Round 10
// 89.543 us; speedup vs baseline: 1.7401x; 1.7401x over previous
//
#include <hip/hip_runtime.h>
#include <hip/hip_bf16.h>

#define EPSF 1e-8f

typedef short bf16x8 __attribute__((ext_vector_type(8)));
typedef float f32x4 __attribute__((ext_vector_type(4)));

// Workspace:
//   Bpk  [loc=8192][lane=64][8 u32]  bf16-packed D-fragment order (16 MiB)
//   shat [loc][c] f32 (4 MiB)
//   pm0/ps0, pm1/ps1/pt1 [2048][32] ; sm*/siz*/entp [256]

__device__ __forceinline__ float bflo(unsigned u){ return __uint_as_float(u<<16); }
__device__ __forceinline__ float bfhi(unsigned u){ return __uint_as_float(u&0xffff0000u); }
__device__ __forceinline__ float bfu16(unsigned short u){ return __uint_as_float((unsigned)u<<16); }
__device__ __forceinline__ unsigned bfpack2(float a,float b){
    return (__float_as_uint(a)>>16)|(__float_as_uint(b)&0xffff0000u);
}
__device__ __forceinline__ unsigned short bfr16(float a){
    return (unsigned short)(__float_as_uint(a)>>16);
}
__device__ __forceinline__ float fastrcp(float x){ return __builtin_amdgcn_rcpf(x); }
__device__ __forceinline__ bf16x8 pack8(const float* v){
    union { unsigned u[4]; bf16x8 v8; } cv;
#pragma unroll
    for (int j = 0; j < 4; ++j) cv.u[j] = bfpack2(v[2*j], v[2*j+1]);
    return cv.v8;
}

// ===========================================================================
// One routing iteration from taps (round-8 structure, slimmed LDS).
// PHASE 0: taps->B1+stats0. PHASE 1: B1->B2+stats1(+T). PHASE 2: B2->shat.
// Block = (b,h,4 w's), 4 waves, wave = 1 loc. Taps gathered straight from the
// persistent slab via ktab (no vL/vTL staging); B transpose buffer in bf16.
//
// LDS map (36480 B -> 4 blocks/CU = 16 waves/CU):
//   0      slab f32[288][12]   (persistent all phase)      13824
//   13824  wLT  u16[28][132]                                7424
//   21248  cbL  f32[128]                                     512
//   21760  smL f32[32] ; 21888 sizL f32[32] ; 22016 ktab u32[32]
//   22144  per-wave[4] x 3584: {Bu u32[32][20]=2560; shL f32[128]=512;
//                               auxL f32[32]=128; statb f32[96]=384}
// ===========================================================================
template<int PHASE>
__global__ __launch_bounds__(256, 4) void k_caps(
    const float* __restrict__ in, const float* __restrict__ cw,
    const float* __restrict__ cb, unsigned* __restrict__ Bpk,
    const float* __restrict__ sm_in, const float* __restrict__ siz_in,
    float* __restrict__ pm, float* __restrict__ ps, float* __restrict__ pt,
    float* __restrict__ shat) {
    __shared__ __align__(16) unsigned char smem[36480];
    float* slab = (float*)smem;                         // [288][12]
    unsigned short* wLT = (unsigned short*)(smem + 13824);
    float* cbL  = (float*)(smem + 21248);
    float* smL  = (float*)(smem + 21760);
    float* sizL = (float*)(smem + 21888);
    unsigned* ktab = (unsigned*)(smem + 22016);

    const int t = threadIdx.x;
    const int lane = t & 63, wid = t >> 6;
    const int bid = blockIdx.x;
    const int bh = bid >> 3, b = bh >> 5, h = bh & 31;
    const int w0 = (bid & 7) << 2;
    const int l15 = lane & 15, lq = lane >> 4;

    unsigned char* wb = smem + 22144 + (size_t)wid * 3584;
    unsigned* Bu  = (unsigned*)wb;                      // [32][20] bf16 pairs
    float* shL    = (float*)(wb + 2560);
    float* auxL   = (float*)(wb + 3072);
    float* statb  = (float*)(wb + 3200);

    // ---- prologue: slab + weights + consts ---------------------------------
    for (int j = t; j < 864; j += 256) {
        const int r = j / 3, q = j - r * 3;
        const int ci2 = r / 9, rem = r - ci2 * 9, kd = rem / 3, dy = rem - kd * 3;
        const int y = h + dy - 1;
        const int x0 = w0 - 4 + q * 4;
        float4 f = {0.f, 0.f, 0.f, 0.f};
        if ((unsigned)y < 32u && (unsigned)x0 < 32u)
            f = *reinterpret_cast<const float4*>(
                in + (((size_t)(b * 32 + ci2) * 8 + kd) * 32 + y) * 32 + x0);
        *reinterpret_cast<float4*>(slab + r * 12 + q * 4) = f;
    }
    for (int j = t; j < 3456; j += 256) {
        const int c = j / 27, k = j - c * 27;
        wLT[k * 132 + c] = bfr16(cw[j]);
    }
    if (t < 128) cbL[t] = cb[t];
    if (t < 32) {
        const int k = t < 27 ? t : 26;      // clamped; kt>=27 masked at use
        const int kd = k / 9, r9 = k - kd * 9, dy = r9 / 3, dx = r9 - dy * 3;
        ktab[t] = (unsigned)((kd * 3 + dy) * 12 + dx);
    }
    if constexpr (PHASE >= 1) {
        if (t < 32) { smL[t] = sm_in[b * 32 + t]; sizL[t] = siz_in[b * 32 + t]; }
    }
    __syncthreads();

    const size_t loc = (size_t)bh * 32 + w0 + wid;
    const int tb = wid + 3;                 // tap col base for this wave

    float b1v[16];
    if constexpr (PHASE == 0) {
        // vsum[k] = sum_ci v[ci][k]  (iter0 uniform-k identity)
        const int k2 = lane >> 1, half = lane & 1;
        float vs = 0.f;
        if (k2 < 27) {
            const float* sp = slab + half * 16 * 108 + ktab[k2] + tb;
#pragma unroll
            for (int i = 0; i < 16; ++i) vs += sp[i * 108];
        }
        vs += __shfl_xor(vs, 1);
        if (half == 0 && k2 < 27) auxL[k2] = vs;
    } else {
        // load previous B (bf16, D-frag order), stage into Bu as ci-pairs
        const uint4* Bg = (const uint4*)(Bpk + loc * 512 + (size_t)lane * 8);
        const uint4 q0 = Bg[0], q1 = Bg[1];
        const unsigned pk[8] = {q0.x, q0.y, q0.z, q0.w, q1.x, q1.y, q1.z, q1.w};
#pragma unroll
        for (int e = 0; e < 8; ++e) { b1v[2*e] = bflo(pk[e]); b1v[2*e+1] = bfhi(pk[e]); }
#pragma unroll
        for (int mt = 0; mt < 2; ++mt)
#pragma unroll
        for (int reg = 0; reg < 4; ++reg)
#pragma unroll
        for (int nt = 0; nt < 2; ++nt) {
            const float me = b1v[mt*8 + nt*4 + reg];
            const float ot = __shfl_xor(me, 1);
            const unsigned pku = (l15 & 1) ? bfpack2(ot, me) : bfpack2(me, ot);
            if ((l15 & 1) == nt)
                Bu[(mt*16 + lq*4 + reg)*20 + nt*8 + (l15 >> 1)] = pku;
        }
        // kmat A-frags: row cj = mt*16+l15, k(ci) = lq*8+j
        bf16x8 kmA[2];
#pragma unroll
        for (int mt = 0; mt < 2; ++mt) {
            const uint4 q = *(const uint4*)(Bu + (mt*16 + l15)*20 + lq*4);
            const unsigned uu[4] = {q.x, q.y, q.z, q.w};
            float ev[8];
#pragma unroll
            for (int j2 = 0; j2 < 4; ++j2) {
                const int ci0 = lq*8 + 2*j2;
                ev[2*j2]   = __expf(bflo(uu[j2]) - smL[ci0])   * sizL[ci0];
                ev[2*j2+1] = __expf(bfhi(uu[j2]) - smL[ci0+1]) * sizL[ci0+1];
            }
            kmA[mt] = pack8(ev);
        }
        // vT B-frags: col kt = nt*16+l15, k(ci) = lq*8+j; kt==27 -> ones col
        bf16x8 vtB[2];
#pragma unroll
        for (int nt = 0; nt < 2; ++nt) {
            const int kt = nt*16 + l15;
            const unsigned ko = ktab[kt];
            float vals[8];
#pragma unroll
            for (int j = 0; j < 8; ++j) {
                const float sv = slab[(lq*8 + j)*108 + ko + tb];
                vals[j] = (kt < 27) ? sv : (kt == 27 ? 1.0f : 0.0f);
            }
            vtB[nt] = pack8(vals);
        }
        // matmul1: u[cj][kt] = kmat x vT ; store to Bu as kt-pairs
        f32x4 accu[2][2];
#pragma unroll
        for (int mt = 0; mt < 2; ++mt)
#pragma unroll
        for (int nt = 0; nt < 2; ++nt)
            accu[mt][nt] = __builtin_amdgcn_mfma_f32_16x16x32_bf16(
                kmA[mt], vtB[nt], (f32x4){0.f,0.f,0.f,0.f}, 0, 0, 0);
#pragma unroll
        for (int mt = 0; mt < 2; ++mt)
#pragma unroll
        for (int reg = 0; reg < 4; ++reg)
#pragma unroll
        for (int nt = 0; nt < 2; ++nt) {
            const float me = accu[mt][nt][reg];
            const float ot = __shfl_xor(me, 1);
            const unsigned pku = (l15 & 1) ? bfpack2(ot, me) : bfpack2(me, ot);
            if ((l15 & 1) == nt)
                Bu[(mt*16 + lq*4 + reg)*20 + nt*8 + (l15 >> 1)] = pku;
        }
    }

    // ---- S + squash (c = lane, lane+64) ------------------------------------
#pragma unroll
    for (int cc = 0; cc < 2; ++cc) {
        const int c = lane + cc * 64;
        float S;
        if constexpr (PHASE == 0) {
            S = 0.f;
#pragma unroll
            for (int k = 0; k < 27; ++k)
                S = fmaf(bfu16(wLT[k*132 + c]), auxL[k], S);
            S = S * (1.0f/32768.0f) + cbL[c] * (1.0f/1024.0f);
        } else {
            const unsigned* up = Bu + (c >> 2) * 20;
            S = 0.f;
#pragma unroll
            for (int p = 0; p < 13; ++p) {
                const unsigned u = up[p];
                S = fmaf(bfu16(wLT[(2*p)*132 + c]),   bflo(u), S);
                S = fmaf(bfu16(wLT[(2*p+1)*132 + c]), bfhi(u), S);
            }
            const unsigned u13 = up[13];
            S = fmaf(bfu16(wLT[26*132 + c]), bflo(u13), S);
            S = fmaf(cbL[c], bfhi(u13), S);        // + cb * K1[cj]
        }
        const float sq = fabsf(S) * S * fastrcp(1.f + S*S + EPSF);
        if constexpr (PHASE == 2) shat[loc * 128 + c] = sq;
        else shL[c] = sq;
    }
    if constexpr (PHASE == 2) return;

    // ---- ws = sum_nj sh*w (bf16, overlays Bu) ; cbs -> auxL ----------------
    {
        const int k0 = 2*l15, k1 = k0 + 1;
#pragma unroll
        for (int i = 0; i < 8; ++i) {
            const int cj = lq + 4*i;
            float v0 = 0.f, v1 = 0.f;
            if (k0 < 27) {
#pragma unroll
                for (int nj = 0; nj < 4; ++nj)
                    v0 = fmaf(shL[cj*4+nj], bfu16(wLT[k0*132 + cj*4 + nj]), v0);
            }
            if (k1 < 27) {
#pragma unroll
                for (int nj = 0; nj < 4; ++nj)
                    v1 = fmaf(shL[cj*4+nj], bfu16(wLT[k1*132 + cj*4 + nj]), v1);
            }
            Bu[cj*20 + l15] = bfpack2(v0, v1);
        }
        if (lane < 32) {
            float cv = 0.f;
#pragma unroll
            for (int nj = 0; nj < 4; ++nj)
                cv = fmaf(shL[lane*4+nj], cbL[lane*4+nj], cv);
            auxL[lane] = cv;
        }
    }

    // ---- matmul2: B_upd = ws x v -------------------------------------------
    bf16x8 wsA[2], vB[2];
#pragma unroll
    for (int mt = 0; mt < 2; ++mt) {
        union { uint4 q4; bf16x8 v8; } cv;
        cv.q4 = *(const uint4*)(Bu + (mt*16 + l15)*20 + lq*4);
        wsA[mt] = cv.v8;
    }
#pragma unroll
    for (int nt = 0; nt < 2; ++nt) {
        const int ci = nt*16 + l15;
        float vals[8];
#pragma unroll
        for (int j = 0; j < 8; ++j) {
            const int k = lq*8 + j;
            const float sv = slab[ci*108 + ktab[k] + tb];
            vals[j] = (k < 27) ? sv : 0.0f;
        }
        vB[nt] = pack8(vals);
    }
    f32x4 accb[2][2];
#pragma unroll
    for (int mt = 0; mt < 2; ++mt)
#pragma unroll
    for (int nt = 0; nt < 2; ++nt)
        accb[mt][nt] = __builtin_amdgcn_mfma_f32_16x16x32_bf16(
            wsA[mt], vB[nt], (f32x4){0.f,0.f,0.f,0.f}, 0, 0, 0);

    // ---- B_new = [B_prev +] upd + cbs ; pack ; store ; stats ---------------
    float bnew[16];
#pragma unroll
    for (int mt = 0; mt < 2; ++mt)
#pragma unroll
    for (int nt = 0; nt < 2; ++nt)
#pragma unroll
    for (int reg = 0; reg < 4; ++reg) {
        float val = accb[mt][nt][reg] + auxL[mt*16 + lq*4 + reg];
        if constexpr (PHASE == 1) val += b1v[mt*8 + nt*4 + reg];
        bnew[mt*8 + nt*4 + reg] = val;
    }
    {
        unsigned pk[8];
#pragma unroll
        for (int e = 0; e < 8; ++e) pk[e] = bfpack2(bnew[2*e], bnew[2*e+1]);
        uint4* Bg = (uint4*)(Bpk + loc * 512 + (size_t)lane * 8);
        Bg[0] = make_uint4(pk[0], pk[1], pk[2], pk[3]);
        Bg[1] = make_uint4(pk[4], pk[5], pk[6], pk[7]);
    }
    float m2[2], s2[2], T2[2];
#pragma unroll
    for (int nt = 0; nt < 2; ++nt) {
        float m = -1e30f;
#pragma unroll
        for (int mt = 0; mt < 2; ++mt)
#pragma unroll
        for (int reg = 0; reg < 4; ++reg) m = fmaxf(m, bnew[mt*8 + nt*4 + reg]);
        float s = 0.f, T = 0.f;
#pragma unroll
        for (int mt = 0; mt < 2; ++mt)
#pragma unroll
        for (int reg = 0; reg < 4; ++reg) {
            const float d = bnew[mt*8 + nt*4 + reg] - m;
            const float e = __expf(d);
            s += e; T += e * d;
        }
        m2[nt] = m; s2[nt] = s; T2[nt] = T;
#pragma unroll
        for (int off = 16; off <= 32; off <<= 1) {   // lanes ^16,^32 share ci
            const float mo = __shfl_xor(m2[nt], off);
            const float so = __shfl_xor(s2[nt], off);
            const float To = __shfl_xor(T2[nt], off);
            const float nm = fmaxf(m2[nt], mo);
            const float ea = __expf(m2[nt]-nm), eb = __expf(mo-nm);
            T2[nt] = ea*(T2[nt] + s2[nt]*(m2[nt]-nm)) + eb*(To + so*(mo-nm));
            s2[nt] = ea*s2[nt] + eb*so;
            m2[nt] = nm;
        }
    }
    if (lane < 16) {
#pragma unroll
        for (int nt = 0; nt < 2; ++nt) {
            const int ci = nt*16 + lane;
            statb[ci] = m2[nt]; statb[32+ci] = s2[nt]; statb[64+ci] = T2[nt];
        }
    }
    __syncthreads();
    if (t < 32) {            // merge 4 waves -> block partial
        float M = -1e30f, Z = 0.f, T = 0.f;
#pragma unroll
        for (int wv = 0; wv < 4; ++wv) {
            const float* sw = (const float*)(smem + 22144 + wv*3584 + 3200);
            const float mo = sw[t], so = sw[32+t], To = sw[64+t];
            const float nm = fmaxf(M, mo);
            const float ea = __expf(M-nm), eb = __expf(mo-nm);
            T = ea*(T + Z*(M-nm)) + eb*(To + so*(mo-nm));
            Z = ea*Z + eb*so;
            M = nm;
        }
        pm[bid*32 + t] = M;
        ps[bid*32 + t] = Z;
        if constexpr (PHASE == 1) pt[bid*32 + t] = T;
    }
}

// ---------------------------------------------------------------------------
// Combine NPART partials per (b,ci) -> sm, siz (+ entropy partial if ENT).
template <int NPART, bool ENT>
__global__ __launch_bounds__(256) void k_comb(const float* __restrict__ pm,
                                              const float* __restrict__ ps,
                                              const float* __restrict__ pt,
                                              float* __restrict__ sm,
                                              float* __restrict__ siz,
                                              float* __restrict__ entp) {
    const int b = blockIdx.x, t = threadIdx.x;
    const int ci = t & 31, seg = t >> 5;
    constexpr int PER = NPART / 8;
    __shared__ float red[3][8][33];

    float M = -1e30f;
    for (int k = 0; k < PER; ++k)
        M = fmaxf(M, pm[((size_t)b * NPART + seg * PER + k) * 32 + ci]);
    red[0][seg][ci] = M;
    __syncthreads();
    float Mg = red[0][0][ci];
#pragma unroll
    for (int q = 1; q < 8; ++q) Mg = fmaxf(Mg, red[0][q][ci]);

    float Z = 0.0f, T = 0.0f;
    for (int k = 0; k < PER; ++k) {
        const size_t i = ((size_t)b * NPART + seg * PER + k) * 32 + ci;
        const float dm = pm[i] - Mg;
        const float e = __expf(dm);
        Z += ps[i] * e;
        if constexpr (ENT) T += (pt[i] + ps[i] * dm) * e;
    }
    red[1][seg][ci] = Z;
    if constexpr (ENT) red[2][seg][ci] = T;
    __syncthreads();
    if (t < 32) {
        float Zt = 0.0f, Tt = 0.0f;
#pragma unroll
        for (int q = 0; q < 8; ++q) {
            Zt += red[1][q][ci];
            if constexpr (ENT) Tt += red[2][q][ci];
        }
        sm[b * 32 + ci] = Mg;
        siz[b * 32 + ci] = 1.0f / Zt;
        if constexpr (ENT)   // ent = (lnZ - T/Z)/ln(32768); eps-in-log ~3e-5
            entp[b * 32 + ci] = (logf(Zt) - Tt / Zt) * (1.0f / 10.39720770839918f);
    }
}

// ---------------------------------------------------------------------------
// shat [b][h][w][c] -> out [b][c][h][w] ; block 0 finalizes entropy.
__global__ __launch_bounds__(256) void k_out(const float* __restrict__ shat,
                                             const float* __restrict__ entp,
                                             float* __restrict__ out) {
    __shared__ float tile[32][129];
    const int bh = blockIdx.x;
    const int b = bh >> 5, h = bh & 31;
    const int t = threadIdx.x;
    const float4* sp = reinterpret_cast<const float4*>(shat + (size_t)bh * 4096);
#pragma unroll
    for (int j = 0; j < 4; ++j) {
        const int idx = t + j * 256;
        const float4 f = sp[idx];
        const int w = idx >> 5;
        const int c4 = (idx & 31) * 4;
        tile[w][c4 + 0] = f.x; tile[w][c4 + 1] = f.y;
        tile[w][c4 + 2] = f.z; tile[w][c4 + 3] = f.w;
    }
    __syncthreads();
    const int c = t >> 1, half = t & 1;
    float* op = out + (((size_t)b * 128 + c) * 32 + h) * 32 + half * 16;
#pragma unroll
    for (int j = 0; j < 16; ++j) op[j] = tile[half * 16 + j][c];

    if (bh == 0) {
        __shared__ float er[256];
        er[t] = entp[t];
        __syncthreads();
        for (int s2 = 128; s2 > 0; s2 >>= 1) {
            if (t < s2) er[t] += er[t + s2];
            __syncthreads();
        }
        if (t == 0) out[1048576] = er[0] * (1.0f / 256.0f);
    }
}

// ---------------------------------------------------------------------------
extern "C" void kernel_launch(void* const* d_in, const int* in_sizes, int n_in,
                              void* d_out, int out_size, void* d_ws, size_t ws_size,
                              hipStream_t stream) {
    const float* in = (const float*)d_in[0];   // (8,32,8,32,32)
    const float* cw = (const float*)d_in[1];   // (128,1,3,3,3)
    const float* cb = (const float*)d_in[2];   // (128,)
    float* out = (float*)d_out;                // 1048576 + 1 floats

    unsigned* Bpk = (unsigned*)d_ws;           // 16 MiB
    float* shat = (float*)(Bpk + 4194304);     // 4 MiB
    float* pm0  = shat + 1048576;              // [2048*32] each
    float* ps0  = pm0 + 65536;
    float* pm1  = ps0 + 65536;
    float* ps1  = pm1 + 65536;
    float* pt1  = ps1 + 65536;
    float* sm0  = pt1 + 65536;                 // [256] each
    float* siz0 = sm0 + 256;
    float* sm1  = siz0 + 256;
    float* siz1 = sm1 + 256;
    float* entp = siz1 + 256;

    k_caps<0><<<2048, 256, 0, stream>>>(in, cw, cb, Bpk, sm0, siz0, pm0, ps0, pt1, shat);
    k_comb<256, false><<<8, 256, 0, stream>>>(pm0, ps0, nullptr, sm0, siz0, nullptr);
    k_caps<1><<<2048, 256, 0, stream>>>(in, cw, cb, Bpk, sm0, siz0, pm1, ps1, pt1, shat);
    k_comb<256, true><<<8, 256, 0, stream>>>(pm1, ps1, pt1, sm1, siz1, entp);
    k_caps<2><<<2048, 256, 0, stream>>>(in, cw, cb, Bpk, sm1, siz1, pm1, ps1, pt1, shat);
    k_out<<<256, 256, 0, stream>>>(shat, entp, out);
}

// Round 11
// 85.615 us; speedup vs baseline: 1.8199x; 1.0459x over previous
//
#include <hip/hip_runtime.h>
#include <hip/hip_bf16.h>

#define EPSF 1e-8f

typedef short bf16x8 __attribute__((ext_vector_type(8)));
typedef float f32x4 __attribute__((ext_vector_type(4)));

// Workspace:
//   Bpk  [loc=8192][lane=64][8 u32]  bf16-packed D-fragment order (16 MiB)
//   pm0/ps0, pm1/ps1/pt1 [2048][32] ; sm*/siz*/entp [256]

__device__ __forceinline__ float bflo(unsigned u){ return __uint_as_float(u<<16); }
__device__ __forceinline__ float bfhi(unsigned u){ return __uint_as_float(u&0xffff0000u); }
__device__ __forceinline__ float bfu16(unsigned short u){ return __uint_as_float((unsigned)u<<16); }
__device__ __forceinline__ unsigned bfpack2(float a,float b){
    return (__float_as_uint(a)>>16)|(__float_as_uint(b)&0xffff0000u);
}
__device__ __forceinline__ unsigned short bfr16(float a){
    return (unsigned short)(__float_as_uint(a)>>16);
}
__device__ __forceinline__ float fastrcp(float x){ return __builtin_amdgcn_rcpf(x); }
__device__ __forceinline__ bf16x8 pack8(const float* v){
    union { unsigned u[4]; bf16x8 v8; } cv;
#pragma unroll
    for (int j = 0; j < 4; ++j) cv.u[j] = bfpack2(v[2*j], v[2*j+1]);
    return cv.v8;
}

// ===========================================================================
// One routing iteration from taps. PHASE 0: taps->B1+stats0. PHASE 1:
// B1->B2+stats1(+T). PHASE 2: B2->out directly (+ entropy finalize, block 0).
// Block = (b,h,4 w's), 4 waves, wave = 1 loc.
//
// LDS map (29568 B -> 5 blocks/CU = 20 waves/CU):
//   0      slabB u16[288][12]  (input taps bf16, persistent)        6912
//   6912   wLT  u16[28][132]                                        7424
//   14336  cbL  f32[128]                                             512
//   14848  smL f32[32] ; 14976 sizL f32[32] ; 15104 ktab u32[32]
//   15232  per-wave[4] x 3584: {Bu u32[32][20]=2560; shL f32[128]=512;
//                               auxL f32[32]=128; statb f32[96]=384}
// ===========================================================================
template<int PHASE>
__global__ __launch_bounds__(256, 5) void k_caps(
    const float* __restrict__ in, const float* __restrict__ cw,
    const float* __restrict__ cb, unsigned* __restrict__ Bpk,
    const float* __restrict__ sm_in, const float* __restrict__ siz_in,
    float* __restrict__ pm, float* __restrict__ ps, float* __restrict__ pt,
    float* __restrict__ outp) {
    __shared__ __align__(16) unsigned char smem[29568];
    unsigned short* slabB = (unsigned short*)smem;       // [288][12] bf16
    unsigned short* wLT = (unsigned short*)(smem + 6912);
    float* cbL  = (float*)(smem + 14336);
    float* smL  = (float*)(smem + 14848);
    float* sizL = (float*)(smem + 14976);
    unsigned* ktab = (unsigned*)(smem + 15104);

    const int t = threadIdx.x;
    const int lane = t & 63, wid = t >> 6;
    const int bid = blockIdx.x;
    const int bh = bid >> 3, b = bh >> 5, h = bh & 31;
    const int w0 = (bid & 7) << 2;
    const int l15 = lane & 15, lq = lane >> 4;

    unsigned char* wb = smem + 15232 + (size_t)wid * 3584;
    unsigned* Bu  = (unsigned*)wb;                      // [32][20] bf16 pairs
    float* shL    = (float*)(wb + 2560);
    float* auxL   = (float*)(wb + 3072);
    float* statb  = (float*)(wb + 3200);

    // ---- prologue: slab (f32->bf16) + weights + consts ---------------------
    for (int j = t; j < 864; j += 256) {
        const int r = j / 3, q = j - r * 3;
        const int ci2 = r / 9, rem = r - ci2 * 9, kd = rem / 3, dy = rem - kd * 3;
        const int y = h + dy - 1;
        const int x0 = w0 - 4 + q * 4;
        float4 f = {0.f, 0.f, 0.f, 0.f};
        if ((unsigned)y < 32u && (unsigned)x0 < 32u)
            f = *reinterpret_cast<const float4*>(
                in + (((size_t)(b * 32 + ci2) * 8 + kd) * 32 + y) * 32 + x0);
        unsigned* sp = (unsigned*)slabB + r * 6 + q * 2;
        sp[0] = bfpack2(f.x, f.y);
        sp[1] = bfpack2(f.z, f.w);
    }
    for (int j = t; j < 3456; j += 256) {
        const int c = j / 27, k = j - c * 27;
        wLT[k * 132 + c] = bfr16(cw[j]);
    }
    if (t < 128) cbL[t] = cb[t];
    if (t < 32) {
        const int k = t < 27 ? t : 26;      // clamped; kt>=27 masked at use
        const int kd = k / 9, r9 = k - kd * 9, dy = r9 / 3, dx = r9 - dy * 3;
        ktab[t] = (unsigned)((kd * 3 + dy) * 12 + dx);
    }
    if constexpr (PHASE >= 1) {
        if (t < 32) { smL[t] = sm_in[b * 32 + t]; sizL[t] = siz_in[b * 32 + t]; }
    }
    __syncthreads();

    const size_t loc = (size_t)bh * 32 + w0 + wid;
    const int tb = wid + 3;                 // tap col base for this wave

    float b1v[16];
    if constexpr (PHASE == 0) {
        // vsum[k] = sum_ci v[ci][k]  (iter0 uniform-k identity)
        const int k2 = lane >> 1, half = lane & 1;
        float vs = 0.f;
        if (k2 < 27) {
            const unsigned short* sp = slabB + half * 16 * 108 + ktab[k2] + tb;
#pragma unroll
            for (int i = 0; i < 16; ++i) vs += bfu16(sp[i * 108]);
        }
        vs += __shfl_xor(vs, 1);
        if (half == 0 && k2 < 27) auxL[k2] = vs;
    } else {
        // load previous B (bf16, D-frag order), stage into Bu as ci-pairs
        const uint4* Bg = (const uint4*)(Bpk + loc * 512 + (size_t)lane * 8);
        const uint4 q0 = Bg[0], q1 = Bg[1];
        const unsigned pk[8] = {q0.x, q0.y, q0.z, q0.w, q1.x, q1.y, q1.z, q1.w};
#pragma unroll
        for (int e = 0; e < 8; ++e) { b1v[2*e] = bflo(pk[e]); b1v[2*e+1] = bfhi(pk[e]); }
#pragma unroll
        for (int mt = 0; mt < 2; ++mt)
#pragma unroll
        for (int reg = 0; reg < 4; ++reg)
#pragma unroll
        for (int nt = 0; nt < 2; ++nt) {
            const float me = b1v[mt*8 + nt*4 + reg];
            const float ot = __shfl_xor(me, 1);
            const unsigned pku = (l15 & 1) ? bfpack2(ot, me) : bfpack2(me, ot);
            if ((l15 & 1) == nt)
                Bu[(mt*16 + lq*4 + reg)*20 + nt*8 + (l15 >> 1)] = pku;
        }
        // kmat A-frags: row cj = mt*16+l15, k(ci) = lq*8+j
        bf16x8 kmA[2];
#pragma unroll
        for (int mt = 0; mt < 2; ++mt) {
            const uint4 q = *(const uint4*)(Bu + (mt*16 + l15)*20 + lq*4);
            const unsigned uu[4] = {q.x, q.y, q.z, q.w};
            float ev[8];
#pragma unroll
            for (int j2 = 0; j2 < 4; ++j2) {
                const int ci0 = lq*8 + 2*j2;
                ev[2*j2]   = __expf(bflo(uu[j2]) - smL[ci0])   * sizL[ci0];
                ev[2*j2+1] = __expf(bfhi(uu[j2]) - smL[ci0+1]) * sizL[ci0+1];
            }
            kmA[mt] = pack8(ev);
        }
        // vT B-frags: col kt = nt*16+l15, k(ci) = lq*8+j; kt==27 -> ones col
        bf16x8 vtB[2];
#pragma unroll
        for (int nt = 0; nt < 2; ++nt) {
            const int kt = nt*16 + l15;
            const unsigned ko = ktab[kt];
            union { unsigned short s[8]; bf16x8 v8; } cv;
#pragma unroll
            for (int j = 0; j < 8; ++j) {
                const unsigned short sv = slabB[(lq*8 + j)*108 + ko + tb];
                cv.s[j] = (kt < 27) ? sv : (unsigned short)(kt == 27 ? 0x3f80 : 0);
            }
            vtB[nt] = cv.v8;
        }
        // matmul1: u[cj][kt] = kmat x vT ; store to Bu as kt-pairs
        f32x4 accu[2][2];
#pragma unroll
        for (int mt = 0; mt < 2; ++mt)
#pragma unroll
        for (int nt = 0; nt < 2; ++nt)
            accu[mt][nt] = __builtin_amdgcn_mfma_f32_16x16x32_bf16(
                kmA[mt], vtB[nt], (f32x4){0.f,0.f,0.f,0.f}, 0, 0, 0);
#pragma unroll
        for (int mt = 0; mt < 2; ++mt)
#pragma unroll
        for (int reg = 0; reg < 4; ++reg)
#pragma unroll
        for (int nt = 0; nt < 2; ++nt) {
            const float me = accu[mt][nt][reg];
            const float ot = __shfl_xor(me, 1);
            const unsigned pku = (l15 & 1) ? bfpack2(ot, me) : bfpack2(me, ot);
            if ((l15 & 1) == nt)
                Bu[(mt*16 + lq*4 + reg)*20 + nt*8 + (l15 >> 1)] = pku;
        }
    }

    // ---- S + squash (c = lane, lane+64) ------------------------------------
#pragma unroll
    for (int cc = 0; cc < 2; ++cc) {
        const int c = lane + cc * 64;
        float S;
        if constexpr (PHASE == 0) {
            S = 0.f;
#pragma unroll
            for (int k = 0; k < 27; ++k)
                S = fmaf(bfu16(wLT[k*132 + c]), auxL[k], S);
            S = S * (1.0f/32768.0f) + cbL[c] * (1.0f/1024.0f);
        } else {
            const unsigned* up = Bu + (c >> 2) * 20;
            S = 0.f;
#pragma unroll
            for (int p = 0; p < 13; ++p) {
                const unsigned u = up[p];
                S = fmaf(bfu16(wLT[(2*p)*132 + c]),   bflo(u), S);
                S = fmaf(bfu16(wLT[(2*p+1)*132 + c]), bfhi(u), S);
            }
            const unsigned u13 = up[13];
            S = fmaf(bfu16(wLT[26*132 + c]), bflo(u13), S);
            S = fmaf(cbL[c], bfhi(u13), S);        // + cb * K1[cj]
        }
        const float sq = fabsf(S) * S * fastrcp(1.f + S*S + EPSF);
        shL[c] = sq;
    }

    if constexpr (PHASE == 2) {
        // epilogue: gather 4 waves' shL -> out [b][c][h][w0..w0+3] (float4)
        __syncthreads();
        if (t < 128) {
            const float* s0 = (const float*)(smem + 15232 + 0*3584 + 2560);
            const float* s1 = (const float*)(smem + 15232 + 1*3584 + 2560);
            const float* s2 = (const float*)(smem + 15232 + 2*3584 + 2560);
            const float* s3 = (const float*)(smem + 15232 + 3*3584 + 2560);
            float4 o = make_float4(s0[t], s1[t], s2[t], s3[t]);
            *reinterpret_cast<float4*>(
                outp + ((size_t)(b*128 + t))*1024 + (size_t)h*32 + w0) = o;
        }
        if (bid == 0) {        // entropy finalize from entp partials (pt arg)
            float* er = (float*)smem;    // slab dead
            er[t] = pt[t];
            __syncthreads();
            for (int s2v = 128; s2v > 0; s2v >>= 1) {
                if (t < s2v) er[t] += er[t + s2v];
                __syncthreads();
            }
            if (t == 0) outp[1048576] = er[0] * (1.0f/256.0f);
        }
        return;
    }

    // ---- ws = sum_nj sh*w (bf16, overlays Bu) ; cbs -> auxL ----------------
    {
        const int k0 = 2*l15, k1 = k0 + 1;
#pragma unroll
        for (int i = 0; i < 8; ++i) {
            const int cj = lq + 4*i;
            float v0 = 0.f, v1 = 0.f;
            if (k0 < 27) {
#pragma unroll
                for (int nj = 0; nj < 4; ++nj)
                    v0 = fmaf(shL[cj*4+nj], bfu16(wLT[k0*132 + cj*4 + nj]), v0);
            }
            if (k1 < 27) {
#pragma unroll
                for (int nj = 0; nj < 4; ++nj)
                    v1 = fmaf(shL[cj*4+nj], bfu16(wLT[k1*132 + cj*4 + nj]), v1);
            }
            Bu[cj*20 + l15] = bfpack2(v0, v1);
        }
        if (lane < 32) {
            float cv = 0.f;
#pragma unroll
            for (int nj = 0; nj < 4; ++nj)
                cv = fmaf(shL[lane*4+nj], cbL[lane*4+nj], cv);
            auxL[lane] = cv;
        }
    }

    // ---- matmul2: B_upd = ws x v -------------------------------------------
    bf16x8 wsA[2], vB[2];
#pragma unroll
    for (int mt = 0; mt < 2; ++mt) {
        union { uint4 q4; bf16x8 v8; } cv;
        cv.q4 = *(const uint4*)(Bu + (mt*16 + l15)*20 + lq*4);
        wsA[mt] = cv.v8;
    }
#pragma unroll
    for (int nt = 0; nt < 2; ++nt) {
        const int ci = nt*16 + l15;
        union { unsigned short s[8]; bf16x8 v8; } cv;
#pragma unroll
        for (int j = 0; j < 8; ++j) {
            const int k = lq*8 + j;
            const unsigned short sv = slabB[ci*108 + ktab[k] + tb];
            cv.s[j] = (k < 27) ? sv : (unsigned short)0;
        }
        vB[nt] = cv.v8;
    }
    f32x4 accb[2][2];
#pragma unroll
    for (int mt = 0; mt < 2; ++mt)
#pragma unroll
    for (int nt = 0; nt < 2; ++nt)
        accb[mt][nt] = __builtin_amdgcn_mfma_f32_16x16x32_bf16(
            wsA[mt], vB[nt], (f32x4){0.f,0.f,0.f,0.f}, 0, 0, 0);

    // ---- B_new = [B_prev +] upd + cbs ; pack ; store ; stats ---------------
    float bnew[16];
#pragma unroll
    for (int mt = 0; mt < 2; ++mt)
#pragma unroll
    for (int nt = 0; nt < 2; ++nt)
#pragma unroll
    for (int reg = 0; reg < 4; ++reg) {
        float val = accb[mt][nt][reg] + auxL[mt*16 + lq*4 + reg];
        if constexpr (PHASE == 1) val += b1v[mt*8 + nt*4 + reg];
        bnew[mt*8 + nt*4 + reg] = val;
    }
    {
        unsigned pk[8];
#pragma unroll
        for (int e = 0; e < 8; ++e) pk[e] = bfpack2(bnew[2*e], bnew[2*e+1]);
        uint4* Bg = (uint4*)(Bpk + loc * 512 + (size_t)lane * 8);
        Bg[0] = make_uint4(pk[0], pk[1], pk[2], pk[3]);
        Bg[1] = make_uint4(pk[4], pk[5], pk[6], pk[7]);
    }
    float m2[2], s2[2], T2[2];
#pragma unroll
    for (int nt = 0; nt < 2; ++nt) {
        float m = -1e30f;
#pragma unroll
        for (int mt = 0; mt < 2; ++mt)
#pragma unroll
        for (int reg = 0; reg < 4; ++reg) m = fmaxf(m, bnew[mt*8 + nt*4 + reg]);
        float s = 0.f, T = 0.f;
#pragma unroll
        for (int mt = 0; mt < 2; ++mt)
#pragma unroll
        for (int reg = 0; reg < 4; ++reg) {
            const float d = bnew[mt*8 + nt*4 + reg] - m;
            const float e = __expf(d);
            s += e; T += e * d;
        }
        m2[nt] = m; s2[nt] = s; T2[nt] = T;
#pragma unroll
        for (int off = 16; off <= 32; off <<= 1) {   // lanes ^16,^32 share ci
            const float mo = __shfl_xor(m2[nt], off);
            const float so = __shfl_xor(s2[nt], off);
            const float To = __shfl_xor(T2[nt], off);
            const float nm = fmaxf(m2[nt], mo);
            const float ea = __expf(m2[nt]-nm), eb = __expf(mo-nm);
            T2[nt] = ea*(T2[nt] + s2[nt]*(m2[nt]-nm)) + eb*(To + so*(mo-nm));
            s2[nt] = ea*s2[nt] + eb*so;
            m2[nt] = nm;
        }
    }
    if (lane < 16) {
#pragma unroll
        for (int nt = 0; nt < 2; ++nt) {
            const int ci = nt*16 + lane;
            statb[ci] = m2[nt]; statb[32+ci] = s2[nt]; statb[64+ci] = T2[nt];
        }
    }
    __syncthreads();
    if (t < 32) {            // merge 4 waves -> block partial
        float M = -1e30f, Z = 0.f, T = 0.f;
#pragma unroll
        for (int wv = 0; wv < 4; ++wv) {
            const float* sw = (const float*)(smem + 15232 + wv*3584 + 3200);
            const float mo = sw[t], so = sw[32+t], To = sw[64+t];
            const float nm = fmaxf(M, mo);
            const float ea = __expf(M-nm), eb = __expf(mo-nm);
            T = ea*(T + Z*(M-nm)) + eb*(To + so*(mo-nm));
            Z = ea*Z + eb*so;
            M = nm;
        }
        pm[bid*32 + t] = M;
        ps[bid*32 + t] = Z;
        if constexpr (PHASE == 1) pt[bid*32 + t] = T;
    }
}

// ---------------------------------------------------------------------------
// Combine NPART partials per (b,ci) -> sm, siz (+ entropy partial if ENT).
template <int NPART, bool ENT>
__global__ __launch_bounds__(256) void k_comb(const float* __restrict__ pm,
                                              const float* __restrict__ ps,
                                              const float* __restrict__ pt,
                                              float* __restrict__ sm,
                                              float* __restrict__ siz,
                                              float* __restrict__ entp) {
    const int b = blockIdx.x, t = threadIdx.x;
    const int ci = t & 31, seg = t >> 5;
    constexpr int PER = NPART / 8;
    __shared__ float red[3][8][33];

    float M = -1e30f;
    for (int k = 0; k < PER; ++k)
        M = fmaxf(M, pm[((size_t)b * NPART + seg * PER + k) * 32 + ci]);
    red[0][seg][ci] = M;
    __syncthreads();
    float Mg = red[0][0][ci];
#pragma unroll
    for (int q = 1; q < 8; ++q) Mg = fmaxf(Mg, red[0][q][ci]);

    float Z = 0.0f, T = 0.0f;
    for (int k = 0; k < PER; ++k) {
        const size_t i = ((size_t)b * NPART + seg * PER + k) * 32 + ci;
        const float dm = pm[i] - Mg;
        const float e = __expf(dm);
        Z += ps[i] * e;
        if constexpr (ENT) T += (pt[i] + ps[i] * dm) * e;
    }
    red[1][seg][ci] = Z;
    if constexpr (ENT) red[2][seg][ci] = T;
    __syncthreads();
    if (t < 32) {
        float Zt = 0.0f, Tt = 0.0f;
#pragma unroll
        for (int q = 0; q < 8; ++q) {
            Zt += red[1][q][ci];
            if constexpr (ENT) Tt += red[2][q][ci];
        }
        sm[b * 32 + ci] = Mg;
        siz[b * 32 + ci] = 1.0f / Zt;
        if constexpr (ENT)   // ent = (lnZ - T/Z)/ln(32768); eps-in-log ~3e-5
            entp[b * 32 + ci] = (logf(Zt) - Tt / Zt) * (1.0f / 10.39720770839918f);
    }
}

// ---------------------------------------------------------------------------
extern "C" void kernel_launch(void* const* d_in, const int* in_sizes, int n_in,
                              void* d_out, int out_size, void* d_ws, size_t ws_size,
                              hipStream_t stream) {
    const float* in = (const float*)d_in[0];   // (8,32,8,32,32)
    const float* cw = (const float*)d_in[1];   // (128,1,3,3,3)
    const float* cb = (const float*)d_in[2];   // (128,)
    float* out = (float*)d_out;                // 1048576 + 1 floats

    unsigned* Bpk = (unsigned*)d_ws;           // 16 MiB
    float* pm0  = (float*)(Bpk + 4194304);     // [2048*32] each
    float* ps0  = pm0 + 65536;
    float* pm1  = ps0 + 65536;
    float* ps1  = pm1 + 65536;
    float* pt1  = ps1 + 65536;
    float* sm0  = pt1 + 65536;                 // [256] each
    float* siz0 = sm0 + 256;
    float* sm1  = siz0 + 256;
    float* siz1 = sm1 + 256;
    float* entp = siz1 + 256;

    k_caps<0><<<2048, 256, 0, stream>>>(in, cw, cb, Bpk, sm0, siz0, pm0, ps0, pt1, out);
    k_comb<256, false><<<8, 256, 0, stream>>>(pm0, ps0, nullptr, sm0, siz0, nullptr);
    k_caps<1><<<2048, 256, 0, stream>>>(in, cw, cb, Bpk, sm0, siz0, pm1, ps1, pt1, out);
    k_comb<256, true><<<8, 256, 0, stream>>>(pm1, ps1, pt1, sm1, siz1, entp);
    k_caps<2><<<2048, 256, 0, stream>>>(in, cw, cb, Bpk, sm1, siz1, pm1, ps1, entp, out);
}